// Round 10
// baseline (203.046 us; speedup 1.0000x reference)
//
#include <hip/hip_runtime.h>
#include <math.h>

#define BB 2
#define SS 192
#define DD 512
#define HH 8
#define HD 64
#define QCB 3                 // q-rows per block
#define NQC (SS / QCB)        // 64 q-chunks
#define PROJ_N (BB*HH*SS*HD)
#define SCL (0.125f * 1.44269504088896f)   // 1/sqrt(64) * log2(e)

typedef __attribute__((ext_vector_type(8))) short bf16x8;
typedef __attribute__((ext_vector_type(4))) float f32x4;
typedef __attribute__((ext_vector_type(4))) unsigned uint4v;
typedef _Float16 f16x8 __attribute__((ext_vector_type(8)));

__device__ __forceinline__ unsigned cvt_pk_bf16(float a, float b) {
    unsigned r;
    asm("v_cvt_pk_bf16_f32 %0, %1, %2" : "=v"(r) : "v"(a), "v"(b));
    return r;
}
// x[0..7] ~= hi + lo (split-bf16) -- used by projection GEMMs
__device__ __forceinline__ void split8_pk(const float* x, uint4v& hi, uint4v& lo) {
#pragma unroll
    for (int p = 0; p < 4; ++p) {
        const float a = x[2 * p], b = x[2 * p + 1];
        const unsigned h = cvt_pk_bf16(a, b);
        const float ra = a - __uint_as_float(h << 16);
        const float rb = b - __uint_as_float(h & 0xFFFF0000u);
        hi[p] = h;
        lo[p] = cvt_pk_bf16(ra, rb);
    }
}

// 8 f32 -> f16x8, RNE (v_cvt_f16_f32)
__device__ __forceinline__ f16x8 cvt8_f16_rne(const float* g) {
    f16x8 r;
#pragma unroll
    for (int i = 0; i < 8; ++i) r[i] = (_Float16)g[i];
    return r;
}

// ---------------------------------------------------------------------------
// Split-bf16 MFMA GEMM: y = x @ W^T   (x: M x 512, W: 512 x 512, f32)
// ---------------------------------------------------------------------------
template <int SPLIT>
__device__ __forceinline__ void gemm_mfma_body(const float* __restrict__ x,
                                               const float* __restrict__ W,
                                               float* __restrict__ y) {
    __shared__ short Ahs[2][4 * 64 * 8], Als[2][4 * 64 * 8];
    __shared__ short Bhs[2][4 * 64 * 8], Bls[2][4 * 64 * 8];

    const int t = threadIdx.x;
    const int lane = t & 63, w = t >> 6;
    const int wr = w >> 1, wc = w & 1;
    const int c16 = lane & 15, q4 = lane >> 4;
    const int m0 = blockIdx.x * 64, n0 = blockIdx.y * 64;
    const int sr = t >> 2, scc = t & 3;

    f32x4 acc[2][2];
#pragma unroll
    for (int a = 0; a < 2; ++a)
#pragma unroll
        for (int b = 0; b < 2; ++b) acc[a][b] = (f32x4){0.f, 0.f, 0.f, 0.f};

#define STAGE(kk, bf)                                                              \
    {                                                                              \
        float a8[8], w8[8];                                                        \
        *(f32x4*)&a8[0] = *(const f32x4*)&x[(m0 + sr) * 512 + (kk) + scc * 8];     \
        *(f32x4*)&a8[4] = *(const f32x4*)&x[(m0 + sr) * 512 + (kk) + scc * 8 + 4]; \
        *(f32x4*)&w8[0] = *(const f32x4*)&W[(n0 + sr) * 512 + (kk) + scc * 8];     \
        *(f32x4*)&w8[4] = *(const f32x4*)&W[(n0 + sr) * 512 + (kk) + scc * 8 + 4]; \
        uint4v h, l;                                                               \
        split8_pk(a8, h, l);                                                       \
        *(uint4v*)&Ahs[bf][(scc * 64 + sr) * 8] = h;                               \
        *(uint4v*)&Als[bf][(scc * 64 + sr) * 8] = l;                               \
        split8_pk(w8, h, l);                                                       \
        *(uint4v*)&Bhs[bf][(scc * 64 + sr) * 8] = h;                               \
        *(uint4v*)&Bls[bf][(scc * 64 + sr) * 8] = l;                               \
    }

    STAGE(0, 0)
    for (int s = 0; s < 16; ++s) {
        __syncthreads();
        if (s + 1 < 16) STAGE((s + 1) * 32, (s + 1) & 1)
        const int b = s & 1;
        bf16x8 aH[2], aL[2], bH[2], bL[2];
#pragma unroll
        for (int mt = 0; mt < 2; ++mt) {
            const int row = wr * 32 + mt * 16 + c16;
            aH[mt] = *(const bf16x8*)&Ahs[b][(q4 * 64 + row) * 8];
            aL[mt] = *(const bf16x8*)&Als[b][(q4 * 64 + row) * 8];
        }
#pragma unroll
        for (int nt = 0; nt < 2; ++nt) {
            const int col = wc * 32 + nt * 16 + c16;
            bH[nt] = *(const bf16x8*)&Bhs[b][(q4 * 64 + col) * 8];
            bL[nt] = *(const bf16x8*)&Bls[b][(q4 * 64 + col) * 8];
        }
#pragma unroll
        for (int mt = 0; mt < 2; ++mt)
#pragma unroll
            for (int nt = 0; nt < 2; ++nt) {
                acc[mt][nt] = __builtin_amdgcn_mfma_f32_16x16x32_bf16(aH[mt], bH[nt], acc[mt][nt], 0, 0, 0);
                acc[mt][nt] = __builtin_amdgcn_mfma_f32_16x16x32_bf16(aH[mt], bL[nt], acc[mt][nt], 0, 0, 0);
                acc[mt][nt] = __builtin_amdgcn_mfma_f32_16x16x32_bf16(aL[mt], bH[nt], acc[mt][nt], 0, 0, 0);
            }
    }
#undef STAGE

#pragma unroll
    for (int mt = 0; mt < 2; ++mt)
#pragma unroll
        for (int nt = 0; nt < 2; ++nt)
#pragma unroll
            for (int j = 0; j < 4; ++j) {
                const int n_row = m0 + wr * 32 + mt * 16 + q4 * 4 + j;
                const int col = n0 + wc * 32 + nt * 16 + c16;
                const float v = acc[mt][nt][j];
                if (SPLIT) {
                    const int b = n_row / SS, s2 = n_row % SS;
                    const int h = col >> 6, e = col & 63;
                    y[((b * HH + h) * SS + s2) * HD + e] = v;
                } else {
                    y[n_row * 512 + col] = v;
                }
            }
}

__global__ __launch_bounds__(256) void proj4_kernel(
    const float* __restrict__ xq, const float* __restrict__ xk,
    const float* __restrict__ xl, const float* __restrict__ xv,
    const float* __restrict__ Wq, const float* __restrict__ Wk,
    const float* __restrict__ Wv, float* __restrict__ ws) {
    const int p = blockIdx.z;
    const float* x = (p == 0) ? xq : (p == 1) ? xk : (p == 2) ? xl : xv;
    const float* W = (p == 0) ? Wq : (p == 3) ? Wv : Wk;
    gemm_mfma_body<1>(x, W, ws + p * PROJ_N);
}

__global__ __launch_bounds__(256) void outproj_kernel(
    const float* __restrict__ att, const float* __restrict__ Wout,
    float* __restrict__ out) {
    gemm_mfma_body<0>(att, Wout, out);
}

// ---------------------------------------------------------------------------
// 4-blocks/CU MFMA rank-3 attention (register-class tuned).
// Grid 1024 = 16 bh x 64 qc (QCB=3). 256 thr = 4 waves (2 lg x 2 kg);
// wave covers 96 l x 96 k. Total regs target <=128 (incl AGPR) so 4 blocks
// co-reside (4 wave-slots/SIMD at the 128 class). acc reused across two
// lt-groups (12 AGPR); per-(q,kt) sum-exp kept in r[3][6] regs; eh-shuffle
// reduction deferred to after the q loop (18 independent chains).
// ---------------------------------------------------------------------------
__global__ __launch_bounds__(256, 4) void attn3d_mfma_kernel(
    const float* __restrict__ qh, const float* __restrict__ kh,
    const float* __restrict__ lh, const float* __restrict__ vh,
    float* __restrict__ att) {
    __shared__ short Kf16[8][193][8];       // [ec][k(+pad)][8] f16: 24.7 KB
    __shared__ short qpk[QCB][8][8];        // [q][ec][8] f16: 384 B
    __shared__ float partial[2][QCB][196];  // [lg][q][k]: 4.7 KB
    __shared__ float Wt[QCB][192];          // 2.3 KB
    __shared__ float zinv[QCB];

    const int blk = blockIdx.x;
    const int bh = blk >> 6, qc = blk & 63;
    const int t = threadIdx.x;
    const int lane = t & 63, w = t >> 6;
    const int lg = w >> 1, kg = w & 1;
    const int c = lane & 15, eh = lane >> 4;

    // ---- stage q rows as f16 (scale+log2e folded) ----
    if (t < QCB * 64) {
        const int q = t >> 6, e = t & 63;
        const float v = qh[(bh * SS + qc * QCB + q) * HD + e] * SCL;
        qpk[q][e >> 3][e & 7] = __builtin_bit_cast(short, (_Float16)v);
    }
    // ---- stage K as f16 frag-major ----
#pragma unroll
    for (int j = 0; j < 6; ++j) {
        const int cid = t + 256 * j;          // 1536 8-elem chunks
        const int k = cid >> 3, ec = cid & 7;
        float b8[8];
        const float* kp = &kh[(bh * SS + k) * HD + ec * 8];
        *(f32x4*)&b8[0] = *(const f32x4*)&kp[0];
        *(f32x4*)&b8[4] = *(const f32x4*)&kp[4];
        *(f16x8*)&Kf16[ec][k][0] = cvt8_f16_rne(b8);
    }
    // ---- A fragments: L rows f16 RNE, q-invariant, in registers ----
    f16x8 Af[6][2];
#pragma unroll
    for (int lt = 0; lt < 6; ++lt)
#pragma unroll
        for (int s = 0; s < 2; ++s) {
            const int row = lg * 96 + lt * 16 + c;
            float b8[8];
            const float* lp = &lh[(bh * SS + row) * HD + s * 32 + eh * 8];
            *(f32x4*)&b8[0] = *(const f32x4*)&lp[0];
            *(f32x4*)&b8[4] = *(const f32x4*)&lp[4];
            Af[lt][s] = cvt8_f16_rne(b8);
        }
    __syncthreads();   // qpk, Kf16 ready

    float r[QCB][6];

    // ---- barrier-free, shuffle-free q loop ----
    for (int q = 0; q < QCB; ++q) {
        f16x8 qf[2];
#pragma unroll
        for (int s = 0; s < 2; ++s)
            qf[s] = *(const f16x8*)&qpk[q][s * 4 + eh][0];   // broadcast
#pragma unroll
        for (int kt = 0; kt < 6; ++kt) {
            const int col = kg * 96 + kt * 16 + c;
            f16x8 Bf[2];
#pragma unroll
            for (int s = 0; s < 2; ++s) {
                const f16x8 Kf = *(const f16x8*)&Kf16[s * 4 + eh][col][0];
                Bf[s] = Kf * qf[s];                          // 4 v_pk_mul_f16
            }
            float rr = 0.f;
#pragma unroll
            for (int g = 0; g < 2; ++g) {       // two lt-groups reuse acc[3]
                f32x4 acc[3];
#pragma unroll
                for (int i = 0; i < 3; ++i) acc[i] = (f32x4){0.f, 0.f, 0.f, 0.f};
#pragma unroll
                for (int i = 0; i < 3; ++i) {
                    const int lt = g * 3 + i;
                    acc[i] = __builtin_amdgcn_mfma_f32_16x16x32_f16(Af[lt][0], Bf[0], acc[i], 0, 0, 0);
                    acc[i] = __builtin_amdgcn_mfma_f32_16x16x32_f16(Af[lt][1], Bf[1], acc[i], 0, 0, 0);
                }
                float r0 = 0.f, r1 = 0.f, r2 = 0.f, r3 = 0.f;
#pragma unroll
                for (int i = 0; i < 3; ++i) {
                    r0 += __builtin_amdgcn_exp2f(acc[i][0]);
                    r1 += __builtin_amdgcn_exp2f(acc[i][1]);
                    r2 += __builtin_amdgcn_exp2f(acc[i][2]);
                    r3 += __builtin_amdgcn_exp2f(acc[i][3]);
                }
                rr += (r0 + r1) + (r2 + r3);
            }
            r[q][kt] = rr;
        }
    }

    // ---- deferred eh-reduction: 18 independent 2-shuffle chains ----
#pragma unroll
    for (int q = 0; q < QCB; ++q)
#pragma unroll
        for (int kt = 0; kt < 6; ++kt) {
            float v = r[q][kt];
            v += __shfl_xor(v, 16, 64);
            v += __shfl_xor(v, 32, 64);
            if (eh == 0) partial[lg][q][kg * 96 + kt * 16 + c] = v;
        }
    __syncthreads();   // all partials written

    // combine lg partials
    for (int id = t; id < QCB * 192; id += 256) {
        const int q = id / 192, k = id - q * 192;
        Wt[q][k] = partial[0][q][k] + partial[1][q][k];
    }
    __syncthreads();

    // Z per q (wave w handles q = w)
    if (w < QCB) {
        const int q = w;
        float z = Wt[q][lane] + Wt[q][lane + 64] + Wt[q][lane + 128];
#pragma unroll
        for (int off = 32; off >= 1; off >>= 1) z += __shfl_xor(z, off, 64);
        if (lane == 0) zinv[q] = 1.f / z;
    }
    __syncthreads();

    // attended: att[q,d] = zinv * sum_k Wt[q][k] * vh[k,d]; 8 loads in flight
    const int b = bh >> 3, h = bh & 7;
    if (t < QCB * 64) {
        const int q = t >> 6, d = t & 63;
        const float* vp = vh + bh * SS * HD + d;
        float sum = 0.f;
        for (int k0 = 0; k0 < SS; k0 += 8) {
            float v8[8];
#pragma unroll
            for (int j = 0; j < 8; ++j) v8[j] = vp[(k0 + j) * HD];
#pragma unroll
            for (int j = 0; j < 8; ++j) sum = fmaf(Wt[q][k0 + j], v8[j], sum);
        }
        att[(b * SS + qc * QCB + q) * DD + h * HD + d] = sum * zinv[q];
    }
}

extern "C" void kernel_launch(void* const* d_in, const int* in_sizes, int n_in,
                              void* d_out, int out_size, void* d_ws, size_t ws_size,
                              hipStream_t stream) {
    (void)in_sizes; (void)n_in; (void)out_size; (void)ws_size;
    const float* q    = (const float*)d_in[0];
    const float* k    = (const float*)d_in[1];
    const float* l    = (const float*)d_in[2];
    const float* v    = (const float*)d_in[3];
    const float* Wq   = (const float*)d_in[4];
    const float* Wk   = (const float*)d_in[5];
    const float* Wv   = (const float*)d_in[6];
    const float* Wout = (const float*)d_in[7];
    float* out = (float*)d_out;

    float* ws  = (float*)d_ws;
    float* qhp = ws + 0 * PROJ_N;
    float* khp = ws + 1 * PROJ_N;
    float* lhp = ws + 2 * PROJ_N;
    float* vhp = ws + 3 * PROJ_N;
    float* atp = ws + 4 * PROJ_N;

    proj4_kernel<<<dim3(384 / 64, 512 / 64, 4), 256, 0, stream>>>(
        q, k, l, v, Wq, Wk, Wv, ws);
    attn3d_mfma_kernel<<<dim3(16 * NQC), 256, 0, stream>>>(qhp, khp, lhp, vhp, atp);
    outproj_kernel<<<dim3(384 / 64, 512 / 64), 256, 0, stream>>>(atp, Wout, out);
}

// Round 11
// 188.321 us; speedup vs baseline: 1.0782x; 1.0782x over previous
//
#include <hip/hip_runtime.h>
#include <math.h>

#define BB 2
#define SS 192
#define DD 512
#define HH 8
#define HD 64
#define QCB 6                 // q-rows per block
#define NQC (SS / QCB)        // 32 q-chunks
#define PROJ_N (BB*HH*SS*HD)
#define SCL (0.125f * 1.44269504088896f)   // 1/sqrt(64) * log2(e)

typedef __attribute__((ext_vector_type(8))) short bf16x8;
typedef __attribute__((ext_vector_type(4))) float f32x4;
typedef __attribute__((ext_vector_type(4))) unsigned uint4v;
typedef _Float16 f16x8 __attribute__((ext_vector_type(8)));

__device__ __forceinline__ unsigned cvt_pk_bf16(float a, float b) {
    unsigned r;
    asm("v_cvt_pk_bf16_f32 %0, %1, %2" : "=v"(r) : "v"(a), "v"(b));
    return r;
}
// x[0..7] ~= hi + lo (split-bf16) -- used by projection GEMMs
__device__ __forceinline__ void split8_pk(const float* x, uint4v& hi, uint4v& lo) {
#pragma unroll
    for (int p = 0; p < 4; ++p) {
        const float a = x[2 * p], b = x[2 * p + 1];
        const unsigned h = cvt_pk_bf16(a, b);
        const float ra = a - __uint_as_float(h << 16);
        const float rb = b - __uint_as_float(h & 0xFFFF0000u);
        hi[p] = h;
        lo[p] = cvt_pk_bf16(ra, rb);
    }
}

// 8 f32 -> f16x8, RNE (v_cvt_f16_f32)
__device__ __forceinline__ f16x8 cvt8_f16_rne(const float* g) {
    f16x8 r;
#pragma unroll
    for (int i = 0; i < 8; ++i) r[i] = (_Float16)g[i];
    return r;
}

// ---------------------------------------------------------------------------
// Split-bf16 MFMA GEMM: y = x @ W^T   (x: M x 512, W: 512 x 512, f32)
// ---------------------------------------------------------------------------
template <int SPLIT>
__device__ __forceinline__ void gemm_mfma_body(const float* __restrict__ x,
                                               const float* __restrict__ W,
                                               float* __restrict__ y) {
    __shared__ short Ahs[2][4 * 64 * 8], Als[2][4 * 64 * 8];
    __shared__ short Bhs[2][4 * 64 * 8], Bls[2][4 * 64 * 8];

    const int t = threadIdx.x;
    const int lane = t & 63, w = t >> 6;
    const int wr = w >> 1, wc = w & 1;
    const int c16 = lane & 15, q4 = lane >> 4;
    const int m0 = blockIdx.x * 64, n0 = blockIdx.y * 64;
    const int sr = t >> 2, scc = t & 3;

    f32x4 acc[2][2];
#pragma unroll
    for (int a = 0; a < 2; ++a)
#pragma unroll
        for (int b = 0; b < 2; ++b) acc[a][b] = (f32x4){0.f, 0.f, 0.f, 0.f};

#define STAGE(kk, bf)                                                              \
    {                                                                              \
        float a8[8], w8[8];                                                        \
        *(f32x4*)&a8[0] = *(const f32x4*)&x[(m0 + sr) * 512 + (kk) + scc * 8];     \
        *(f32x4*)&a8[4] = *(const f32x4*)&x[(m0 + sr) * 512 + (kk) + scc * 8 + 4]; \
        *(f32x4*)&w8[0] = *(const f32x4*)&W[(n0 + sr) * 512 + (kk) + scc * 8];     \
        *(f32x4*)&w8[4] = *(const f32x4*)&W[(n0 + sr) * 512 + (kk) + scc * 8 + 4]; \
        uint4v h, l;                                                               \
        split8_pk(a8, h, l);                                                       \
        *(uint4v*)&Ahs[bf][(scc * 64 + sr) * 8] = h;                               \
        *(uint4v*)&Als[bf][(scc * 64 + sr) * 8] = l;                               \
        split8_pk(w8, h, l);                                                       \
        *(uint4v*)&Bhs[bf][(scc * 64 + sr) * 8] = h;                               \
        *(uint4v*)&Bls[bf][(scc * 64 + sr) * 8] = l;                               \
    }

    STAGE(0, 0)
    for (int s = 0; s < 16; ++s) {
        __syncthreads();
        if (s + 1 < 16) STAGE((s + 1) * 32, (s + 1) & 1)
        const int b = s & 1;
        bf16x8 aH[2], aL[2], bH[2], bL[2];
#pragma unroll
        for (int mt = 0; mt < 2; ++mt) {
            const int row = wr * 32 + mt * 16 + c16;
            aH[mt] = *(const bf16x8*)&Ahs[b][(q4 * 64 + row) * 8];
            aL[mt] = *(const bf16x8*)&Als[b][(q4 * 64 + row) * 8];
        }
#pragma unroll
        for (int nt = 0; nt < 2; ++nt) {
            const int col = wc * 32 + nt * 16 + c16;
            bH[nt] = *(const bf16x8*)&Bhs[b][(q4 * 64 + col) * 8];
            bL[nt] = *(const bf16x8*)&Bls[b][(q4 * 64 + col) * 8];
        }
#pragma unroll
        for (int mt = 0; mt < 2; ++mt)
#pragma unroll
            for (int nt = 0; nt < 2; ++nt) {
                acc[mt][nt] = __builtin_amdgcn_mfma_f32_16x16x32_bf16(aH[mt], bH[nt], acc[mt][nt], 0, 0, 0);
                acc[mt][nt] = __builtin_amdgcn_mfma_f32_16x16x32_bf16(aH[mt], bL[nt], acc[mt][nt], 0, 0, 0);
                acc[mt][nt] = __builtin_amdgcn_mfma_f32_16x16x32_bf16(aL[mt], bH[nt], acc[mt][nt], 0, 0, 0);
            }
    }
#undef STAGE

#pragma unroll
    for (int mt = 0; mt < 2; ++mt)
#pragma unroll
        for (int nt = 0; nt < 2; ++nt)
#pragma unroll
            for (int j = 0; j < 4; ++j) {
                const int n_row = m0 + wr * 32 + mt * 16 + q4 * 4 + j;
                const int col = n0 + wc * 32 + nt * 16 + c16;
                const float v = acc[mt][nt][j];
                if (SPLIT) {
                    const int b = n_row / SS, s2 = n_row % SS;
                    const int h = col >> 6, e = col & 63;
                    y[((b * HH + h) * SS + s2) * HD + e] = v;
                } else {
                    y[n_row * 512 + col] = v;
                }
            }
}

__global__ __launch_bounds__(256) void proj4_kernel(
    const float* __restrict__ xq, const float* __restrict__ xk,
    const float* __restrict__ xl, const float* __restrict__ xv,
    const float* __restrict__ Wq, const float* __restrict__ Wk,
    const float* __restrict__ Wv, float* __restrict__ ws) {
    const int p = blockIdx.z;
    const float* x = (p == 0) ? xq : (p == 1) ? xk : (p == 2) ? xl : xv;
    const float* W = (p == 0) ? Wq : (p == 3) ? Wv : Wk;
    gemm_mfma_body<1>(x, W, ws + p * PROJ_N);
}

__global__ __launch_bounds__(256) void outproj_kernel(
    const float* __restrict__ att, const float* __restrict__ Wout,
    float* __restrict__ out) {
    gemm_mfma_body<0>(att, Wout, out);
}

// ---------------------------------------------------------------------------
// 16-waves/CU MFMA rank-3 attention (both operands in LDS, slim waves).
// Grid 512 = 16 bh x 32 qc (QCB=6) = 2 blocks/CU. 512 thr = 8 waves
// (2 lg x 4 kg); wave covers 96 l x 48 k. K and L both f16 frag-major in
// LDS; A-frag read per (q,lt) (2 ds_read_b128), B = K*q per (q,kt).
// Per-thread live set ~95-110 regs; __launch_bounds__(512,4) caps at 128
// -> 16 waves/CU (2x R9). q-loop fully unrolled so r[][] stays in regs.
// ---------------------------------------------------------------------------
__global__ __launch_bounds__(512, 4) void attn3d_mfma_kernel(
    const float* __restrict__ qh, const float* __restrict__ kh,
    const float* __restrict__ lh, const float* __restrict__ vh,
    float* __restrict__ att) {
    __shared__ short Kf16[8][193][8];       // [ec][k(+pad)][8] f16: 24.7 KB
    __shared__ short Lf16[8][193][8];       // [ec][l(+pad)][8] f16: 24.7 KB
    __shared__ short qpk[QCB][8][8];        // [q][ec][8] f16: 768 B
    __shared__ float partial[2][QCB][196];  // [lg][q][k]: 9.4 KB
    __shared__ float Wt[QCB][192];          // 4.6 KB
    __shared__ float zinv[QCB];

    const int blk = blockIdx.x;
    const int bh = blk >> 5, qc = blk & 31;
    const int t = threadIdx.x;
    const int lane = t & 63, w = t >> 6;
    const int lg = w >> 2, kg = w & 3;
    const int c = lane & 15, eh = lane >> 4;

    // ---- stage q rows as f16 (scale+log2e folded) ----
    if (t < QCB * 64) {
        const int q = t >> 6, e = t & 63;
        const float v = qh[(bh * SS + qc * QCB + q) * HD + e] * SCL;
        qpk[q][e >> 3][e & 7] = __builtin_bit_cast(short, (_Float16)v);
    }
    // ---- stage K and L as f16 frag-major ----
#pragma unroll
    for (int j = 0; j < 3; ++j) {
        const int cid = t + 512 * j;          // 1536 8-elem chunks each
        const int k = cid >> 3, ec = cid & 7;
        float b8[8];
        const float* kp = &kh[(bh * SS + k) * HD + ec * 8];
        *(f32x4*)&b8[0] = *(const f32x4*)&kp[0];
        *(f32x4*)&b8[4] = *(const f32x4*)&kp[4];
        *(f16x8*)&Kf16[ec][k][0] = cvt8_f16_rne(b8);
        const float* lp = &lh[(bh * SS + k) * HD + ec * 8];
        *(f32x4*)&b8[0] = *(const f32x4*)&lp[0];
        *(f32x4*)&b8[4] = *(const f32x4*)&lp[4];
        *(f16x8*)&Lf16[ec][k][0] = cvt8_f16_rne(b8);
    }
    __syncthreads();   // qpk, Kf16, Lf16 ready

    float r[QCB][3];
#pragma unroll
    for (int q = 0; q < QCB; ++q)
#pragma unroll
        for (int kt = 0; kt < 3; ++kt) r[q][kt] = 0.f;

    // ---- barrier-free q loop (fully unrolled: r[][] statically indexed) ----
#pragma unroll
    for (int q = 0; q < QCB; ++q) {
        f16x8 qf[2];
#pragma unroll
        for (int s = 0; s < 2; ++s)
            qf[s] = *(const f16x8*)&qpk[q][s * 4 + eh][0];   // broadcast
        // B fragments for this q (3 kt x 2 s)
        f16x8 Bf[3][2];
#pragma unroll
        for (int kt = 0; kt < 3; ++kt)
#pragma unroll
            for (int s = 0; s < 2; ++s) {
                const f16x8 Kf = *(const f16x8*)&Kf16[s * 4 + eh][kg * 48 + kt * 16 + c][0];
                Bf[kt][s] = Kf * qf[s];                      // 4 v_pk_mul_f16
            }
#pragma unroll
        for (int lt = 0; lt < 6; ++lt) {
            const int row = lg * 96 + lt * 16 + c;
            const f16x8 A0 = *(const f16x8*)&Lf16[eh][row][0];
            const f16x8 A1 = *(const f16x8*)&Lf16[4 + eh][row][0];
            f32x4 acc[3];
#pragma unroll
            for (int kt = 0; kt < 3; ++kt) acc[kt] = (f32x4){0.f, 0.f, 0.f, 0.f};
#pragma unroll
            for (int kt = 0; kt < 3; ++kt) {
                acc[kt] = __builtin_amdgcn_mfma_f32_16x16x32_f16(A0, Bf[kt][0], acc[kt], 0, 0, 0);
                acc[kt] = __builtin_amdgcn_mfma_f32_16x16x32_f16(A1, Bf[kt][1], acc[kt], 0, 0, 0);
            }
#pragma unroll
            for (int kt = 0; kt < 3; ++kt) {
                r[q][kt] += (__builtin_amdgcn_exp2f(acc[kt][0]) + __builtin_amdgcn_exp2f(acc[kt][1])) +
                            (__builtin_amdgcn_exp2f(acc[kt][2]) + __builtin_amdgcn_exp2f(acc[kt][3]));
            }
        }
    }

    // ---- deferred eh-reduction: 18 independent 2-shuffle chains ----
#pragma unroll
    for (int q = 0; q < QCB; ++q)
#pragma unroll
        for (int kt = 0; kt < 3; ++kt) {
            float v = r[q][kt];
            v += __shfl_xor(v, 16, 64);
            v += __shfl_xor(v, 32, 64);
            if (eh == 0) partial[lg][q][kg * 48 + kt * 16 + c] = v;
        }
    __syncthreads();   // all partials written

    // combine lg partials
    for (int id = t; id < QCB * 192; id += 512) {
        const int q = id / 192, k = id - q * 192;
        Wt[q][k] = partial[0][q][k] + partial[1][q][k];
    }
    __syncthreads();

    // Z per q (wave w handles q = w)
    if (w < QCB) {
        const int q = w;
        float z = Wt[q][lane] + Wt[q][lane + 64] + Wt[q][lane + 128];
#pragma unroll
        for (int off = 32; off >= 1; off >>= 1) z += __shfl_xor(z, off, 64);
        if (lane == 0) zinv[q] = 1.f / z;
    }
    __syncthreads();

    // attended: att[q,d] = zinv * sum_k Wt[q][k] * vh[k,d]; 8 loads in flight
    const int b = bh >> 3, h = bh & 7;
    if (t < QCB * 64) {
        const int q = t >> 6, d = t & 63;
        const float* vp = vh + bh * SS * HD + d;
        float sum = 0.f;
        for (int k0 = 0; k0 < SS; k0 += 8) {
            float v8[8];
#pragma unroll
            for (int j = 0; j < 8; ++j) v8[j] = vp[(k0 + j) * HD];
#pragma unroll
            for (int j = 0; j < 8; ++j) sum = fmaf(Wt[q][k0 + j], v8[j], sum);
        }
        att[(b * SS + qc * QCB + q) * DD + h * HD + d] = sum * zinv[q];
    }
}

extern "C" void kernel_launch(void* const* d_in, const int* in_sizes, int n_in,
                              void* d_out, int out_size, void* d_ws, size_t ws_size,
                              hipStream_t stream) {
    (void)in_sizes; (void)n_in; (void)out_size; (void)ws_size;
    const float* q    = (const float*)d_in[0];
    const float* k    = (const float*)d_in[1];
    const float* l    = (const float*)d_in[2];
    const float* v    = (const float*)d_in[3];
    const float* Wq   = (const float*)d_in[4];
    const float* Wk   = (const float*)d_in[5];
    const float* Wv   = (const float*)d_in[6];
    const float* Wout = (const float*)d_in[7];
    float* out = (float*)d_out;

    float* ws  = (float*)d_ws;
    float* qhp = ws + 0 * PROJ_N;
    float* khp = ws + 1 * PROJ_N;
    float* lhp = ws + 2 * PROJ_N;
    float* vhp = ws + 3 * PROJ_N;
    float* atp = ws + 4 * PROJ_N;

    proj4_kernel<<<dim3(384 / 64, 512 / 64, 4), 256, 0, stream>>>(
        q, k, l, v, Wq, Wk, Wv, ws);
    attn3d_mfma_kernel<<<dim3(16 * NQC), 512, 0, stream>>>(qhp, khp, lhp, vhp, atp);
    outproj_kernel<<<dim3(384 / 64, 512 / 64), 256, 0, stream>>>(atp, Wout, out);
}

// Round 12
// 67.053 us; speedup vs baseline: 3.0281x; 2.8085x over previous
//
#include <hip/hip_runtime.h>
#include <math.h>

#define BB 2
#define SS 192
#define DD 512
#define HH 8
#define HD 64
#define QCB 6                 // q-rows per block
#define NQC (SS / QCB)        // 32 q-chunks
#define PROJ_N (BB*HH*SS*HD)
#define SCL (0.125f * 1.44269504088896f)   // 1/sqrt(64) * log2(e)

typedef __attribute__((ext_vector_type(8))) short bf16x8;
typedef __attribute__((ext_vector_type(4))) float f32x4;
typedef __attribute__((ext_vector_type(4))) unsigned uint4v;
typedef _Float16 f16x8 __attribute__((ext_vector_type(8)));

__device__ __forceinline__ unsigned cvt_pk_bf16(float a, float b) {
    unsigned r;
    asm("v_cvt_pk_bf16_f32 %0, %1, %2" : "=v"(r) : "v"(a), "v"(b));
    return r;
}
// x[0..7] ~= hi + lo (split-bf16) -- used by projection GEMMs
__device__ __forceinline__ void split8_pk(const float* x, uint4v& hi, uint4v& lo) {
#pragma unroll
    for (int p = 0; p < 4; ++p) {
        const float a = x[2 * p], b = x[2 * p + 1];
        const unsigned h = cvt_pk_bf16(a, b);
        const float ra = a - __uint_as_float(h << 16);
        const float rb = b - __uint_as_float(h & 0xFFFF0000u);
        hi[p] = h;
        lo[p] = cvt_pk_bf16(ra, rb);
    }
}

// 8 f32 -> f16x8, RNE (v_cvt_f16_f32)
__device__ __forceinline__ f16x8 cvt8_f16_rne(const float* g) {
    f16x8 r;
#pragma unroll
    for (int i = 0; i < 8; ++i) r[i] = (_Float16)g[i];
    return r;
}

// ---------------------------------------------------------------------------
// Split-bf16 MFMA GEMM: y = x @ W^T   (x: M x 512, W: 512 x 512, f32)
// ---------------------------------------------------------------------------
template <int SPLIT>
__device__ __forceinline__ void gemm_mfma_body(const float* __restrict__ x,
                                               const float* __restrict__ W,
                                               float* __restrict__ y) {
    __shared__ short Ahs[2][4 * 64 * 8], Als[2][4 * 64 * 8];
    __shared__ short Bhs[2][4 * 64 * 8], Bls[2][4 * 64 * 8];

    const int t = threadIdx.x;
    const int lane = t & 63, w = t >> 6;
    const int wr = w >> 1, wc = w & 1;
    const int c16 = lane & 15, q4 = lane >> 4;
    const int m0 = blockIdx.x * 64, n0 = blockIdx.y * 64;
    const int sr = t >> 2, scc = t & 3;

    f32x4 acc[2][2];
#pragma unroll
    for (int a = 0; a < 2; ++a)
#pragma unroll
        for (int b = 0; b < 2; ++b) acc[a][b] = (f32x4){0.f, 0.f, 0.f, 0.f};

#define STAGE(kk, bf)                                                              \
    {                                                                              \
        float a8[8], w8[8];                                                        \
        *(f32x4*)&a8[0] = *(const f32x4*)&x[(m0 + sr) * 512 + (kk) + scc * 8];     \
        *(f32x4*)&a8[4] = *(const f32x4*)&x[(m0 + sr) * 512 + (kk) + scc * 8 + 4]; \
        *(f32x4*)&w8[0] = *(const f32x4*)&W[(n0 + sr) * 512 + (kk) + scc * 8];     \
        *(f32x4*)&w8[4] = *(const f32x4*)&W[(n0 + sr) * 512 + (kk) + scc * 8 + 4]; \
        uint4v h, l;                                                               \
        split8_pk(a8, h, l);                                                       \
        *(uint4v*)&Ahs[bf][(scc * 64 + sr) * 8] = h;                               \
        *(uint4v*)&Als[bf][(scc * 64 + sr) * 8] = l;                               \
        split8_pk(w8, h, l);                                                       \
        *(uint4v*)&Bhs[bf][(scc * 64 + sr) * 8] = h;                               \
        *(uint4v*)&Bls[bf][(scc * 64 + sr) * 8] = l;                               \
    }

    STAGE(0, 0)
    for (int s = 0; s < 16; ++s) {
        __syncthreads();
        if (s + 1 < 16) STAGE((s + 1) * 32, (s + 1) & 1)
        const int b = s & 1;
        bf16x8 aH[2], aL[2], bH[2], bL[2];
#pragma unroll
        for (int mt = 0; mt < 2; ++mt) {
            const int row = wr * 32 + mt * 16 + c16;
            aH[mt] = *(const bf16x8*)&Ahs[b][(q4 * 64 + row) * 8];
            aL[mt] = *(const bf16x8*)&Als[b][(q4 * 64 + row) * 8];
        }
#pragma unroll
        for (int nt = 0; nt < 2; ++nt) {
            const int col = wc * 32 + nt * 16 + c16;
            bH[nt] = *(const bf16x8*)&Bhs[b][(q4 * 64 + col) * 8];
            bL[nt] = *(const bf16x8*)&Bls[b][(q4 * 64 + col) * 8];
        }
#pragma unroll
        for (int mt = 0; mt < 2; ++mt)
#pragma unroll
            for (int nt = 0; nt < 2; ++nt) {
                acc[mt][nt] = __builtin_amdgcn_mfma_f32_16x16x32_bf16(aH[mt], bH[nt], acc[mt][nt], 0, 0, 0);
                acc[mt][nt] = __builtin_amdgcn_mfma_f32_16x16x32_bf16(aH[mt], bL[nt], acc[mt][nt], 0, 0, 0);
                acc[mt][nt] = __builtin_amdgcn_mfma_f32_16x16x32_bf16(aL[mt], bH[nt], acc[mt][nt], 0, 0, 0);
            }
    }
#undef STAGE

#pragma unroll
    for (int mt = 0; mt < 2; ++mt)
#pragma unroll
        for (int nt = 0; nt < 2; ++nt)
#pragma unroll
            for (int j = 0; j < 4; ++j) {
                const int n_row = m0 + wr * 32 + mt * 16 + q4 * 4 + j;
                const int col = n0 + wc * 32 + nt * 16 + c16;
                const float v = acc[mt][nt][j];
                if (SPLIT) {
                    const int b = n_row / SS, s2 = n_row % SS;
                    const int h = col >> 6, e = col & 63;
                    y[((b * HH + h) * SS + s2) * HD + e] = v;
                } else {
                    y[n_row * 512 + col] = v;
                }
            }
}

__global__ __launch_bounds__(256) void proj4_kernel(
    const float* __restrict__ xq, const float* __restrict__ xk,
    const float* __restrict__ xl, const float* __restrict__ xv,
    const float* __restrict__ Wq, const float* __restrict__ Wk,
    const float* __restrict__ Wv, float* __restrict__ ws) {
    const int p = blockIdx.z;
    const float* x = (p == 0) ? xq : (p == 1) ? xk : (p == 2) ? xl : xv;
    const float* W = (p == 0) ? Wq : (p == 3) ? Wv : Wk;
    gemm_mfma_body<1>(x, W, ws + p * PROJ_N);
}

__global__ __launch_bounds__(256) void outproj_kernel(
    const float* __restrict__ att, const float* __restrict__ Wout,
    float* __restrict__ out) {
    gemm_mfma_body<0>(att, Wout, out);
}

// ---------------------------------------------------------------------------
// LDS-atomic MFMA rank-3 attention (no cross-q register state).
// Grid 512 = 16 bh x 32 qc (QCB=6) = 2 blocks/CU. 512 thr = 8 waves
// (2 lg x 4 kg); wave covers 96 l x 48 k. K and L f16 frag-major in LDS.
// Per (q,kt): Bf = K*q (2 ds_read + 8 pk_mul); 6x {A-read, 2 MFMA, 4 exp};
// one atomicAdd (ds_add_f32) into Wt[q][col]. Runtime q loop; no r[][]
// array (R10 scratch bug), no q-unroll (R11 spill bug). Live set ~80 regs;
// __launch_bounds__(512,4) -> 128-class -> 16 waves/CU.
// ---------------------------------------------------------------------------
__global__ __launch_bounds__(512, 4) void attn3d_mfma_kernel(
    const float* __restrict__ qh, const float* __restrict__ kh,
    const float* __restrict__ lh, const float* __restrict__ vh,
    float* __restrict__ att) {
    __shared__ short Kf16[8][193][8];       // [ec][k(+pad)][8] f16: 24.7 KB
    __shared__ short Lf16[8][193][8];       // [ec][l(+pad)][8] f16: 24.7 KB
    __shared__ short qpk[QCB][8][8];        // [q][ec][8] f16: 768 B
    __shared__ float Wt[QCB][192];          // accumulated weights: 4.6 KB
    __shared__ float zinv[QCB];

    const int blk = blockIdx.x;
    const int bh = blk >> 5, qc = blk & 31;
    const int t = threadIdx.x;
    const int lane = t & 63, w = t >> 6;
    const int lg = w >> 2, kg = w & 3;
    const int c = lane & 15, eh = lane >> 4;

    // ---- zero Wt ----
    for (int id = t; id < QCB * 192; id += 512)
        ((float*)Wt)[id] = 0.f;
    // ---- stage q rows as f16 (scale+log2e folded) ----
    if (t < QCB * 64) {
        const int q = t >> 6, e = t & 63;
        const float v = qh[(bh * SS + qc * QCB + q) * HD + e] * SCL;
        qpk[q][e >> 3][e & 7] = __builtin_bit_cast(short, (_Float16)v);
    }
    // ---- stage K and L as f16 frag-major ----
#pragma unroll
    for (int j = 0; j < 3; ++j) {
        const int cid = t + 512 * j;          // 1536 8-elem chunks each
        const int k = cid >> 3, ec = cid & 7;
        float b8[8];
        const float* kp = &kh[(bh * SS + k) * HD + ec * 8];
        *(f32x4*)&b8[0] = *(const f32x4*)&kp[0];
        *(f32x4*)&b8[4] = *(const f32x4*)&kp[4];
        *(f16x8*)&Kf16[ec][k][0] = cvt8_f16_rne(b8);
        const float* lp = &lh[(bh * SS + k) * HD + ec * 8];
        *(f32x4*)&b8[0] = *(const f32x4*)&lp[0];
        *(f32x4*)&b8[4] = *(const f32x4*)&lp[4];
        *(f16x8*)&Lf16[ec][k][0] = cvt8_f16_rne(b8);
    }
    __syncthreads();   // Wt zeroed; qpk, Kf16, Lf16 ready

    // ---- runtime q loop, no cross-q register state ----
    for (int q = 0; q < QCB; ++q) {
        const f16x8 qf0 = *(const f16x8*)&qpk[q][eh][0];
        const f16x8 qf1 = *(const f16x8*)&qpk[q][4 + eh][0];
#pragma unroll
        for (int kt = 0; kt < 3; ++kt) {
            const int col = kg * 48 + kt * 16 + c;
            const f16x8 Bf0 = *(const f16x8*)&Kf16[eh][col][0] * qf0;
            const f16x8 Bf1 = *(const f16x8*)&Kf16[4 + eh][col][0] * qf1;
            float rr = 0.f;
#pragma unroll
            for (int lt = 0; lt < 6; ++lt) {
                const int row = lg * 96 + lt * 16 + c;
                const f16x8 A0 = *(const f16x8*)&Lf16[eh][row][0];
                const f16x8 A1 = *(const f16x8*)&Lf16[4 + eh][row][0];
                f32x4 acc = (f32x4){0.f, 0.f, 0.f, 0.f};
                acc = __builtin_amdgcn_mfma_f32_16x16x32_f16(A0, Bf0, acc, 0, 0, 0);
                acc = __builtin_amdgcn_mfma_f32_16x16x32_f16(A1, Bf1, acc, 0, 0, 0);
                rr += (__builtin_amdgcn_exp2f(acc[0]) + __builtin_amdgcn_exp2f(acc[1])) +
                      (__builtin_amdgcn_exp2f(acc[2]) + __builtin_amdgcn_exp2f(acc[3]));
            }
            atomicAdd(&Wt[q][col], rr);   // ds_add_f32
        }
    }
    __syncthreads();   // all weights accumulated

    // Z per q (wave w handles q = w)
    if (w < QCB) {
        const int q = w;
        float z = Wt[q][lane] + Wt[q][lane + 64] + Wt[q][lane + 128];
#pragma unroll
        for (int off = 32; off >= 1; off >>= 1) z += __shfl_xor(z, off, 64);
        if (lane == 0) zinv[q] = 1.f / z;
    }
    __syncthreads();

    // attended: att[q,d] = zinv * sum_k Wt[q][k] * vh[k,d]; 8 loads in flight
    const int b = bh >> 3, h = bh & 7;
    if (t < QCB * 64) {
        const int q = t >> 6, d = t & 63;
        const float* vp = vh + bh * SS * HD + d;
        float sum = 0.f;
        for (int k0 = 0; k0 < SS; k0 += 8) {
            float v8[8];
#pragma unroll
            for (int j = 0; j < 8; ++j) v8[j] = vp[(k0 + j) * HD];
#pragma unroll
            for (int j = 0; j < 8; ++j) sum = fmaf(Wt[q][k0 + j], v8[j], sum);
        }
        att[(b * SS + qc * QCB + q) * DD + h * HD + d] = sum * zinv[q];
    }
}

extern "C" void kernel_launch(void* const* d_in, const int* in_sizes, int n_in,
                              void* d_out, int out_size, void* d_ws, size_t ws_size,
                              hipStream_t stream) {
    (void)in_sizes; (void)n_in; (void)out_size; (void)ws_size;
    const float* q    = (const float*)d_in[0];
    const float* k    = (const float*)d_in[1];
    const float* l    = (const float*)d_in[2];
    const float* v    = (const float*)d_in[3];
    const float* Wq   = (const float*)d_in[4];
    const float* Wk   = (const float*)d_in[5];
    const float* Wv   = (const float*)d_in[6];
    const float* Wout = (const float*)d_in[7];
    float* out = (float*)d_out;

    float* ws  = (float*)d_ws;
    float* qhp = ws + 0 * PROJ_N;
    float* khp = ws + 1 * PROJ_N;
    float* lhp = ws + 2 * PROJ_N;
    float* vhp = ws + 3 * PROJ_N;
    float* atp = ws + 4 * PROJ_N;

    proj4_kernel<<<dim3(384 / 64, 512 / 64, 4), 256, 0, stream>>>(
        q, k, l, v, Wq, Wk, Wv, ws);
    attn3d_mfma_kernel<<<dim3(16 * NQC), 512, 0, stream>>>(qhp, khp, lhp, vhp, atp);
    outproj_kernel<<<dim3(384 / 64, 512 / 64), 256, 0, stream>>>(atp, Wout, out);
}

// Round 13
// 50.035 us; speedup vs baseline: 4.0580x; 1.3401x over previous
//
#include <hip/hip_runtime.h>
#include <math.h>

#define BB 2
#define SS 192
#define DD 512
#define HH 8
#define HD 64
#define QCB 6                 // q-rows per block
#define NQC (SS / QCB)        // 32 q-chunks
#define PROJ_N (BB*HH*SS*HD)
#define SCL (0.125f * 1.44269504088896f)   // 1/sqrt(64) * log2(e)

typedef __attribute__((ext_vector_type(8))) short bf16x8;
typedef __attribute__((ext_vector_type(4))) float f32x4;
typedef __attribute__((ext_vector_type(4))) unsigned uint4v;
typedef _Float16 f16x8 __attribute__((ext_vector_type(8)));

// 8 f32 -> f16x8, RNE (v_cvt_f16_f32)
__device__ __forceinline__ f16x8 cvt8_f16_rne(const float* g) {
    f16x8 r;
#pragma unroll
    for (int i = 0; i < 8; ++i) r[i] = (_Float16)g[i];
    return r;
}

// ---------------------------------------------------------------------------
// Single-f16 MFMA GEMM: y = x @ W^T  (x: M x 512, W: 512 x 512, f32 in).
// 64x64 tile / block, 256 thr (4 waves, 2x2), BK=32, double-buffered LDS.
// f16 RNE rounding of both operands: proj error ~5e-4 abs (safe vs 6.2e-3).
// ---------------------------------------------------------------------------
template <int SPLIT>
__device__ __forceinline__ void gemm_mfma_body(const float* __restrict__ x,
                                               const float* __restrict__ W,
                                               float* __restrict__ y) {
    __shared__ short Ahs[2][4 * 64 * 8];   // [buf][kchunk][row][8] f16: 8 KB
    __shared__ short Bhs[2][4 * 64 * 8];

    const int t = threadIdx.x;
    const int lane = t & 63, w = t >> 6;
    const int wr = w >> 1, wc = w & 1;
    const int c16 = lane & 15, q4 = lane >> 4;
    const int m0 = blockIdx.x * 64, n0 = blockIdx.y * 64;
    const int sr = t >> 2, scc = t & 3;

    f32x4 acc[2][2];
#pragma unroll
    for (int a = 0; a < 2; ++a)
#pragma unroll
        for (int b = 0; b < 2; ++b) acc[a][b] = (f32x4){0.f, 0.f, 0.f, 0.f};

#define STAGE(kk, bf)                                                              \
    {                                                                              \
        float a8[8], w8[8];                                                        \
        *(f32x4*)&a8[0] = *(const f32x4*)&x[(m0 + sr) * 512 + (kk) + scc * 8];     \
        *(f32x4*)&a8[4] = *(const f32x4*)&x[(m0 + sr) * 512 + (kk) + scc * 8 + 4]; \
        *(f32x4*)&w8[0] = *(const f32x4*)&W[(n0 + sr) * 512 + (kk) + scc * 8];     \
        *(f32x4*)&w8[4] = *(const f32x4*)&W[(n0 + sr) * 512 + (kk) + scc * 8 + 4]; \
        *(f16x8*)&Ahs[bf][(scc * 64 + sr) * 8] = cvt8_f16_rne(a8);                 \
        *(f16x8*)&Bhs[bf][(scc * 64 + sr) * 8] = cvt8_f16_rne(w8);                 \
    }

    STAGE(0, 0)
    for (int s = 0; s < 16; ++s) {
        __syncthreads();
        if (s + 1 < 16) STAGE((s + 1) * 32, (s + 1) & 1)
        const int b = s & 1;
        f16x8 aH[2], bH[2];
#pragma unroll
        for (int mt = 0; mt < 2; ++mt) {
            const int row = wr * 32 + mt * 16 + c16;
            aH[mt] = *(const f16x8*)&Ahs[b][(q4 * 64 + row) * 8];
        }
#pragma unroll
        for (int nt = 0; nt < 2; ++nt) {
            const int col = wc * 32 + nt * 16 + c16;
            bH[nt] = *(const f16x8*)&Bhs[b][(q4 * 64 + col) * 8];
        }
#pragma unroll
        for (int mt = 0; mt < 2; ++mt)
#pragma unroll
            for (int nt = 0; nt < 2; ++nt)
                acc[mt][nt] = __builtin_amdgcn_mfma_f32_16x16x32_f16(aH[mt], bH[nt], acc[mt][nt], 0, 0, 0);
    }
#undef STAGE

#pragma unroll
    for (int mt = 0; mt < 2; ++mt)
#pragma unroll
        for (int nt = 0; nt < 2; ++nt)
#pragma unroll
            for (int j = 0; j < 4; ++j) {
                const int n_row = m0 + wr * 32 + mt * 16 + q4 * 4 + j;
                const int col = n0 + wc * 32 + nt * 16 + c16;
                const float v = acc[mt][nt][j];
                if (SPLIT) {
                    const int b = n_row / SS, s2 = n_row % SS;
                    const int h = col >> 6, e = col & 63;
                    y[((b * HH + h) * SS + s2) * HD + e] = v;
                } else {
                    y[n_row * 512 + col] = v;
                }
            }
}

__global__ __launch_bounds__(256) void proj4_kernel(
    const float* __restrict__ xq, const float* __restrict__ xk,
    const float* __restrict__ xl, const float* __restrict__ xv,
    const float* __restrict__ Wq, const float* __restrict__ Wk,
    const float* __restrict__ Wv, float* __restrict__ ws) {
    const int p = blockIdx.z;
    const float* x = (p == 0) ? xq : (p == 1) ? xk : (p == 2) ? xl : xv;
    const float* W = (p == 0) ? Wq : (p == 3) ? Wv : Wk;
    gemm_mfma_body<1>(x, W, ws + p * PROJ_N);
}

__global__ __launch_bounds__(256) void outproj_kernel(
    const float* __restrict__ att, const float* __restrict__ Wout,
    float* __restrict__ out) {
    gemm_mfma_body<0>(att, Wout, out);
}

// ---------------------------------------------------------------------------
// MFMA rank-3 attention: both operands LDS-staged, B hoisted per q.
// Grid 512 = 16 bh x 32 qc (QCB=6) = 2 blocks/CU. 512 thr = 8 waves
// (2 lg x 4 kg); wave covers 96 l x 48 k. Per q: Bf[3][2] built once
// (6 ds_read + 24 pk_mul, 24 VGPR); inner lt loop reads A once (2 ds_read)
// and feeds 3 kt accs -> 20 ds_read/q (vs 42 in R12). No atomics: 3
// independent 2-shuffle chains per q, eh==0 stores partials. Runtime q
// loop, no cross-q register state. Live ~100 regs; (512,4) = 128 class.
// ---------------------------------------------------------------------------
__global__ __launch_bounds__(512, 4) void attn3d_mfma_kernel(
    const float* __restrict__ qh, const float* __restrict__ kh,
    const float* __restrict__ lh, const float* __restrict__ vh,
    float* __restrict__ att) {
    __shared__ short Kf16[8][193][8];       // [ec][k(+pad)][8] f16: 24.7 KB
    __shared__ short Lf16[8][193][8];       // [ec][l(+pad)][8] f16: 24.7 KB
    __shared__ short qpk[QCB][8][8];        // [q][ec][8] f16: 768 B
    __shared__ float partial[2][QCB][196];  // [lg][q][k(+pad)]: 9.4 KB
    __shared__ float Wt[QCB][192];          // 4.6 KB
    __shared__ float zinv[QCB];

    const int blk = blockIdx.x;
    const int bh = blk >> 5, qc = blk & 31;
    const int t = threadIdx.x;
    const int lane = t & 63, w = t >> 6;
    const int lg = w >> 2, kg = w & 3;
    const int c = lane & 15, eh = lane >> 4;

    // ---- stage q rows as f16 (scale+log2e folded) ----
    if (t < QCB * 64) {
        const int q = t >> 6, e = t & 63;
        const float v = qh[(bh * SS + qc * QCB + q) * HD + e] * SCL;
        qpk[q][e >> 3][e & 7] = __builtin_bit_cast(short, (_Float16)v);
    }
    // ---- stage K and L as f16 frag-major ----
#pragma unroll
    for (int j = 0; j < 3; ++j) {
        const int cid = t + 512 * j;          // 1536 8-elem chunks each
        const int k = cid >> 3, ec = cid & 7;
        float b8[8];
        const float* kp = &kh[(bh * SS + k) * HD + ec * 8];
        *(f32x4*)&b8[0] = *(const f32x4*)&kp[0];
        *(f32x4*)&b8[4] = *(const f32x4*)&kp[4];
        *(f16x8*)&Kf16[ec][k][0] = cvt8_f16_rne(b8);
        const float* lp = &lh[(bh * SS + k) * HD + ec * 8];
        *(f32x4*)&b8[0] = *(const f32x4*)&lp[0];
        *(f32x4*)&b8[4] = *(const f32x4*)&lp[4];
        *(f16x8*)&Lf16[ec][k][0] = cvt8_f16_rne(b8);
    }
    __syncthreads();   // qpk, Kf16, Lf16 ready

    // ---- runtime q loop; B hoisted per q; no cross-q register state ----
    for (int q = 0; q < QCB; ++q) {
        const f16x8 qf0 = *(const f16x8*)&qpk[q][eh][0];
        const f16x8 qf1 = *(const f16x8*)&qpk[q][4 + eh][0];
        f16x8 Bf[3][2];
#pragma unroll
        for (int kt = 0; kt < 3; ++kt) {
            const int col = kg * 48 + kt * 16 + c;
            Bf[kt][0] = *(const f16x8*)&Kf16[eh][col][0] * qf0;
            Bf[kt][1] = *(const f16x8*)&Kf16[4 + eh][col][0] * qf1;
        }
        float rr0 = 0.f, rr1 = 0.f, rr2 = 0.f;
#pragma unroll
        for (int lt = 0; lt < 6; ++lt) {
            const int row = lg * 96 + lt * 16 + c;
            const f16x8 A0 = *(const f16x8*)&Lf16[eh][row][0];
            const f16x8 A1 = *(const f16x8*)&Lf16[4 + eh][row][0];
            f32x4 a0 = (f32x4){0.f, 0.f, 0.f, 0.f};
            f32x4 a1 = (f32x4){0.f, 0.f, 0.f, 0.f};
            f32x4 a2 = (f32x4){0.f, 0.f, 0.f, 0.f};
            a0 = __builtin_amdgcn_mfma_f32_16x16x32_f16(A0, Bf[0][0], a0, 0, 0, 0);
            a1 = __builtin_amdgcn_mfma_f32_16x16x32_f16(A0, Bf[1][0], a1, 0, 0, 0);
            a2 = __builtin_amdgcn_mfma_f32_16x16x32_f16(A0, Bf[2][0], a2, 0, 0, 0);
            a0 = __builtin_amdgcn_mfma_f32_16x16x32_f16(A1, Bf[0][1], a0, 0, 0, 0);
            a1 = __builtin_amdgcn_mfma_f32_16x16x32_f16(A1, Bf[1][1], a1, 0, 0, 0);
            a2 = __builtin_amdgcn_mfma_f32_16x16x32_f16(A1, Bf[2][1], a2, 0, 0, 0);
            rr0 += (__builtin_amdgcn_exp2f(a0[0]) + __builtin_amdgcn_exp2f(a0[1])) +
                   (__builtin_amdgcn_exp2f(a0[2]) + __builtin_amdgcn_exp2f(a0[3]));
            rr1 += (__builtin_amdgcn_exp2f(a1[0]) + __builtin_amdgcn_exp2f(a1[1])) +
                   (__builtin_amdgcn_exp2f(a1[2]) + __builtin_amdgcn_exp2f(a1[3]));
            rr2 += (__builtin_amdgcn_exp2f(a2[0]) + __builtin_amdgcn_exp2f(a2[1])) +
                   (__builtin_amdgcn_exp2f(a2[2]) + __builtin_amdgcn_exp2f(a2[3]));
        }
        // 3 independent shuffle chains (ILP-overlapped)
        rr0 += __shfl_xor(rr0, 16, 64);
        rr1 += __shfl_xor(rr1, 16, 64);
        rr2 += __shfl_xor(rr2, 16, 64);
        rr0 += __shfl_xor(rr0, 32, 64);
        rr1 += __shfl_xor(rr1, 32, 64);
        rr2 += __shfl_xor(rr2, 32, 64);
        if (eh == 0) {
            partial[lg][q][kg * 48 + 0 * 16 + c] = rr0;
            partial[lg][q][kg * 48 + 1 * 16 + c] = rr1;
            partial[lg][q][kg * 48 + 2 * 16 + c] = rr2;
        }
    }
    __syncthreads();   // all partials written

    // combine lg partials
    for (int id = t; id < QCB * 192; id += 512) {
        const int q = id / 192, k = id - q * 192;
        Wt[q][k] = partial[0][q][k] + partial[1][q][k];
    }
    __syncthreads();

    // Z per q (wave w handles q = w)
    if (w < QCB) {
        const int q = w;
        float z = Wt[q][lane] + Wt[q][lane + 64] + Wt[q][lane + 128];
#pragma unroll
        for (int off = 32; off >= 1; off >>= 1) z += __shfl_xor(z, off, 64);
        if (lane == 0) zinv[q] = 1.f / z;
    }
    __syncthreads();

    // attended: att[q,d] = zinv * sum_k Wt[q][k] * vh[k,d]; 8 loads in flight
    const int b = bh >> 3, h = bh & 7;
    if (t < QCB * 64) {
        const int q = t >> 6, d = t & 63;
        const float* vp = vh + bh * SS * HD + d;
        float sum = 0.f;
        for (int k0 = 0; k0 < SS; k0 += 8) {
            float v8[8];
#pragma unroll
            for (int j = 0; j < 8; ++j) v8[j] = vp[(k0 + j) * HD];
#pragma unroll
            for (int j = 0; j < 8; ++j) sum = fmaf(Wt[q][k0 + j], v8[j], sum);
        }
        att[(b * SS + qc * QCB + q) * DD + h * HD + d] = sum * zinv[q];
    }
}

extern "C" void kernel_launch(void* const* d_in, const int* in_sizes, int n_in,
                              void* d_out, int out_size, void* d_ws, size_t ws_size,
                              hipStream_t stream) {
    (void)in_sizes; (void)n_in; (void)out_size; (void)ws_size;
    const float* q    = (const float*)d_in[0];
    const float* k    = (const float*)d_in[1];
    const float* l    = (const float*)d_in[2];
    const float* v    = (const float*)d_in[3];
    const float* Wq   = (const float*)d_in[4];
    const float* Wk   = (const float*)d_in[5];
    const float* Wv   = (const float*)d_in[6];
    const float* Wout = (const float*)d_in[7];
    float* out = (float*)d_out;

    float* ws  = (float*)d_ws;
    float* qhp = ws + 0 * PROJ_N;
    float* khp = ws + 1 * PROJ_N;
    float* lhp = ws + 2 * PROJ_N;
    float* vhp = ws + 3 * PROJ_N;
    float* atp = ws + 4 * PROJ_N;

    proj4_kernel<<<dim3(384 / 64, 512 / 64, 4), 256, 0, stream>>>(
        q, k, l, v, Wq, Wk, Wv, ws);
    attn3d_mfma_kernel<<<dim3(16 * NQC), 512, 0, stream>>>(qhp, khp, lhp, vhp, atp);
    outproj_kernel<<<dim3(384 / 64, 512 / 64), 256, 0, stream>>>(atp, Wout, out);
}